// Round 6
// baseline (316.808 us; speedup 1.0000x reference)
//
#include <hip/hip_runtime.h>

typedef short bf16x8 __attribute__((ext_vector_type(8)));
typedef float f32x4 __attribute__((ext_vector_type(4)));

#define ELLK 32
#define OCAP 4096

// round-to-nearest-even f32 -> bf16
static __device__ __forceinline__ unsigned short f2bf(float f) {
  unsigned u = __float_as_uint(f);
  u += 0x7FFFu + ((u >> 16) & 1u);
  return (unsigned short)(u >> 16);
}
// packed pair of bf16 (low = first elem) -> float2
static __device__ __forceinline__ float2 bf2x2(unsigned u) {
  float2 r;
  r.x = __uint_as_float(u << 16);
  r.y = __uint_as_float(u & 0xFFFF0000u);
  return r;
}
static __device__ __forceinline__ bf16x8 pack_bf8(float4 a, float4 b) {
  bf16x8 r;
  r[0] = (short)f2bf(a.x); r[1] = (short)f2bf(a.y);
  r[2] = (short)f2bf(a.z); r[3] = (short)f2bf(a.w);
  r[4] = (short)f2bf(b.x); r[5] = (short)f2bf(b.y);
  r[6] = (short)f2bf(b.z); r[7] = (short)f2bf(b.w);
  return r;
}

// ---------- setup: zero cnt/ocount + transpose weights to bf16 Wt[n][k] ----------
__global__ void k_setup(const float* __restrict__ W1, const float* __restrict__ Wmu,
                        const float* __restrict__ Wlv, unsigned short* __restrict__ Wt1,
                        unsigned short* __restrict__ Wt2, int* __restrict__ cnt,
                        int* __restrict__ ocount, int n, int nbz) {
  int b = blockIdx.x;
  if (b < nbz) {
    int i = b * 256 + threadIdx.x;
    if (i < n) cnt[i] = 0;
    if (b == 0 && threadIdx.x == 0) *ocount = 0;
  } else {
    int id = (b - nbz) * 256 + threadIdx.x;  // 0..32767
    if (id < 16384) {
      int nn = id >> 7, k = id & 127;
      Wt1[id] = f2bf(W1[k * 128 + nn]);
    } else {
      int id2 = id - 16384;
      int nn = id2 >> 7, k = id2 & 127;
      float v = (nn < 64) ? Wmu[k * 64 + nn] : Wlv[k * 64 + (nn - 64)];
      Wt2[id2] = f2bf(v);
    }
  }
}

// ---------- fused per-block: edge-slice ELL fill + GEMM1 tile (MFMA) ----------
// A(bf16) = x(f32) @ W1 via Wt1[n][k]; block tile 64 rows x 128 cols, 4 waves.
// A/B fragments loaded direct from global (Wt1 is L2-hot); LDS only for the
// coalesced epilogue repack (17 KB -> ~8 blocks/CU).
__global__ __launch_bounds__(256) void k_gemm1_fill(
    const float* __restrict__ x, const unsigned short* __restrict__ Wt,
    unsigned short* __restrict__ A, const int* __restrict__ ei,
    int* __restrict__ cnt, int* __restrict__ ell, int2* __restrict__ ovf,
    int* __restrict__ ocount, int n, int E, int epb) {
  __shared__ unsigned short Xl[64 * 136];
  const int tid = threadIdx.x;

  // ---- edge slice: pos = atomicAdd(cnt[dst]); ell[dst*ELLK+pos] = src ----
  {
    int base = blockIdx.x * epb;
    int lim = base + epb;
    if (lim > E) lim = E;
    for (int e = base + tid; e < lim; e += 256) {
      int s = ei[e];
      int d = ei[E + e];
      int pos = atomicAdd(&cnt[d], 1);
      if (pos < ELLK) {
        ell[d * ELLK + pos] = s;
      } else {
        int o = atomicAdd(ocount, 1);
        if (o < OCAP) ovf[o] = make_int2(d, s);
      }
    }
  }

  // ---- gemm tile ----
  const int row0 = blockIdx.x * 64;
  const int wave = tid >> 6, lane = tid & 63;
  const int li = lane & 15, quad = lane >> 4;
  const int m0 = wave * 16;
  const int grow = row0 + m0 + li;
  const bool rv = grow < n;
  const float4* xr = (const float4*)(x + (size_t)grow * 128);

  f32x4 acc[8];
#pragma unroll
  for (int t = 0; t < 8; ++t) acc[t] = (f32x4){0.f, 0.f, 0.f, 0.f};

#pragma unroll
  for (int kk = 0; kk < 4; ++kk) {
    bf16x8 a;
    if (rv) {
      float4 v0 = xr[kk * 8 + quad * 2];
      float4 v1 = xr[kk * 8 + quad * 2 + 1];
      a = pack_bf8(v0, v1);
    } else {
      a = (bf16x8){0, 0, 0, 0, 0, 0, 0, 0};
    }
#pragma unroll
    for (int nt = 0; nt < 8; ++nt) {
      bf16x8 b = *(const bf16x8*)&Wt[(nt * 16 + li) * 128 + kk * 32 + quad * 8];
      acc[nt] = __builtin_amdgcn_mfma_f32_16x16x32_bf16(a, b, acc[nt], 0, 0, 0);
    }
  }
  // epilogue: repack through LDS for coalesced 16B stores
#pragma unroll
  for (int nt = 0; nt < 8; ++nt)
#pragma unroll
    for (int r = 0; r < 4; ++r)
      Xl[(m0 + quad * 4 + r) * 136 + nt * 16 + li] = f2bf(acc[nt][r]);
  __syncthreads();
  {
    uint4* A4 = (uint4*)A;
#pragma unroll
    for (int i = 0; i < 4; ++i) {
      int idx = tid + i * 256;  // 0..1023
      int r = idx >> 4, c = idx & 15;
      int gi = row0 + r;
      if (gi < n) A4[(size_t)gi * 16 + c] = *(uint4*)&Xl[r * 136 + c * 8];
    }
  }
}

// ---------- SpMM aggregation over ELL (gather-only, bf16 table, f32 accumulate) ----------
// one 64-lane wave per node; lane = 2 channels (packed uint)
template <bool EPI_RELU>
__global__ __launch_bounds__(256) void k_spmm(
    const int* __restrict__ cnt, const int* __restrict__ ell,
    const int2* __restrict__ ovf, const int* __restrict__ ocount,
    const unsigned* __restrict__ S, unsigned* __restrict__ D,
    const float2* __restrict__ bias, int n) {
  int wid = (blockIdx.x * blockDim.x + threadIdx.x) >> 6;
  if (wid >= n) return;
  int lane = threadIdx.x & 63;

  int c = cnt[wid];
  float dsd = rsqrtf((float)(c + 1));
  float idg = dsd * dsd;
  float2 v = bf2x2(S[(size_t)wid * 64 + lane]);
  float2 acc = make_float2(v.x * idg, v.y * idg);

  const int* row = ell + (size_t)wid * ELLK;
  int m = (c < ELLK) ? c : ELLK;
  int j = 0;
  for (; j + 7 < m; j += 8) {
    int4 sa = *(const int4*)(row + j);
    int4 sb = *(const int4*)(row + j + 4);
    unsigned p0 = S[(size_t)sa.x * 64 + lane];
    unsigned p1 = S[(size_t)sa.y * 64 + lane];
    unsigned p2 = S[(size_t)sa.z * 64 + lane];
    unsigned p3 = S[(size_t)sa.w * 64 + lane];
    unsigned p4 = S[(size_t)sb.x * 64 + lane];
    unsigned p5 = S[(size_t)sb.y * 64 + lane];
    unsigned p6 = S[(size_t)sb.z * 64 + lane];
    unsigned p7 = S[(size_t)sb.w * 64 + lane];
    int c0 = cnt[sa.x], c1 = cnt[sa.y], c2 = cnt[sa.z], c3 = cnt[sa.w];
    int c4 = cnt[sb.x], c5 = cnt[sb.y], c6 = cnt[sb.z], c7 = cnt[sb.w];
    float n0 = dsd * rsqrtf((float)(c0 + 1));
    float n1 = dsd * rsqrtf((float)(c1 + 1));
    float n2 = dsd * rsqrtf((float)(c2 + 1));
    float n3 = dsd * rsqrtf((float)(c3 + 1));
    float n4 = dsd * rsqrtf((float)(c4 + 1));
    float n5 = dsd * rsqrtf((float)(c5 + 1));
    float n6 = dsd * rsqrtf((float)(c6 + 1));
    float n7 = dsd * rsqrtf((float)(c7 + 1));
    float2 u;
    u = bf2x2(p0); acc.x = fmaf(n0, u.x, acc.x); acc.y = fmaf(n0, u.y, acc.y);
    u = bf2x2(p1); acc.x = fmaf(n1, u.x, acc.x); acc.y = fmaf(n1, u.y, acc.y);
    u = bf2x2(p2); acc.x = fmaf(n2, u.x, acc.x); acc.y = fmaf(n2, u.y, acc.y);
    u = bf2x2(p3); acc.x = fmaf(n3, u.x, acc.x); acc.y = fmaf(n3, u.y, acc.y);
    u = bf2x2(p4); acc.x = fmaf(n4, u.x, acc.x); acc.y = fmaf(n4, u.y, acc.y);
    u = bf2x2(p5); acc.x = fmaf(n5, u.x, acc.x); acc.y = fmaf(n5, u.y, acc.y);
    u = bf2x2(p6); acc.x = fmaf(n6, u.x, acc.x); acc.y = fmaf(n6, u.y, acc.y);
    u = bf2x2(p7); acc.x = fmaf(n7, u.x, acc.x); acc.y = fmaf(n7, u.y, acc.y);
  }
  for (; j + 3 < m; j += 4) {
    int4 sa = *(const int4*)(row + j);
    unsigned p0 = S[(size_t)sa.x * 64 + lane];
    unsigned p1 = S[(size_t)sa.y * 64 + lane];
    unsigned p2 = S[(size_t)sa.z * 64 + lane];
    unsigned p3 = S[(size_t)sa.w * 64 + lane];
    int c0 = cnt[sa.x], c1 = cnt[sa.y], c2 = cnt[sa.z], c3 = cnt[sa.w];
    float n0 = dsd * rsqrtf((float)(c0 + 1));
    float n1 = dsd * rsqrtf((float)(c1 + 1));
    float n2 = dsd * rsqrtf((float)(c2 + 1));
    float n3 = dsd * rsqrtf((float)(c3 + 1));
    float2 u;
    u = bf2x2(p0); acc.x = fmaf(n0, u.x, acc.x); acc.y = fmaf(n0, u.y, acc.y);
    u = bf2x2(p1); acc.x = fmaf(n1, u.x, acc.x); acc.y = fmaf(n1, u.y, acc.y);
    u = bf2x2(p2); acc.x = fmaf(n2, u.x, acc.x); acc.y = fmaf(n2, u.y, acc.y);
    u = bf2x2(p3); acc.x = fmaf(n3, u.x, acc.x); acc.y = fmaf(n3, u.y, acc.y);
  }
  for (; j < m; ++j) {
    int s = row[j];
    float n0 = dsd * rsqrtf((float)(cnt[s] + 1));
    float2 u0 = bf2x2(S[(size_t)s * 64 + lane]);
    acc.x = fmaf(n0, u0.x, acc.x); acc.y = fmaf(n0, u0.y, acc.y);
  }
  if (c > ELLK) {  // pathological high-degree nodes: scan tiny overflow list
    int oc = *ocount;
    if (oc > OCAP) oc = OCAP;
    for (int k = 0; k < oc; ++k) {
      int2 e = ovf[k];
      if (e.x == wid) {
        float n0 = dsd * rsqrtf((float)(cnt[e.y] + 1));
        float2 u0 = bf2x2(S[(size_t)e.y * 64 + lane]);
        acc.x = fmaf(n0, u0.x, acc.x); acc.y = fmaf(n0, u0.y, acc.y);
      }
    }
  }
  if (EPI_RELU) {
    float2 b = bias[lane];
    acc.x = fmaxf(acc.x + b.x, 0.f);
    acc.y = fmaxf(acc.y + b.y, 0.f);
  }
  unsigned pk = (unsigned)f2bf(acc.x) | ((unsigned)f2bf(acc.y) << 16);
  D[(size_t)wid * 64 + lane] = pk;
}

// ---------- GEMM2 (MFMA, zero LDS): out = [G@Wmu+bmu | G@Wlv+blv] via Wt2[n][k] ----------
__global__ __launch_bounds__(256) void k_gemm2_mfma(
    const unsigned short* __restrict__ G, const unsigned short* __restrict__ Wt,
    const float* __restrict__ bmu, const float* __restrict__ blv,
    float* __restrict__ out, int n) {
  const int tid = threadIdx.x;
  const int row0 = blockIdx.x * 64;
  const int wave = tid >> 6, lane = tid & 63;
  const int li = lane & 15, quad = lane >> 4;
  const int m0 = wave * 16;
  const int grow = row0 + m0 + li;
  const bool rv = grow < n;
  const unsigned short* gr = G + (size_t)grow * 128;

  f32x4 acc[8];
#pragma unroll
  for (int t = 0; t < 8; ++t) acc[t] = (f32x4){0.f, 0.f, 0.f, 0.f};

#pragma unroll
  for (int kk = 0; kk < 4; ++kk) {
    bf16x8 a = rv ? *(const bf16x8*)(gr + kk * 32 + quad * 8)
                  : (bf16x8){0, 0, 0, 0, 0, 0, 0, 0};
#pragma unroll
    for (int nt = 0; nt < 8; ++nt) {
      bf16x8 b = *(const bf16x8*)&Wt[(nt * 16 + li) * 128 + kk * 32 + quad * 8];
      acc[nt] = __builtin_amdgcn_mfma_f32_16x16x32_bf16(a, b, acc[nt], 0, 0, 0);
    }
  }
  float bias[8];
#pragma unroll
  for (int nt = 0; nt < 8; ++nt) {
    int c = nt * 16 + li;
    bias[nt] = (c < 64) ? bmu[c] : blv[c - 64];
  }
#pragma unroll
  for (int nt = 0; nt < 8; ++nt) {
    int col = nt * 16 + li;
#pragma unroll
    for (int r = 0; r < 4; ++r) {
      int gi = row0 + m0 + quad * 4 + r;
      if (gi < n) {
        float v = acc[nt][r] + bias[nt];
        if (col < 64) out[(size_t)gi * 64 + col] = v;              // mu
        else          out[(size_t)(n + gi) * 64 + (col - 64)] = v; // logvar
      }
    }
  }
}

extern "C" void kernel_launch(void* const* d_in, const int* in_sizes, int n_in,
                              void* d_out, int out_size, void* d_ws, size_t ws_size,
                              hipStream_t stream) {
  const float* x   = (const float*)d_in[0];
  const int*   ei  = (const int*)d_in[1];   // [2, E], row0 = src, row1 = dst
  const float* W1  = (const float*)d_in[3];
  const float* b1  = (const float*)d_in[4];
  const float* Wmu = (const float*)d_in[5];
  const float* bmu = (const float*)d_in[6];
  const float* Wlv = (const float*)d_in[7];
  const float* blv = (const float*)d_in[8];
  float* out = (float*)d_out;

  const int n = in_sizes[0] / 128;
  const int E = in_sizes[1] / 2;

  // workspace layout (float units)
  float* ws = (float*)d_ws;
  size_t p = 0;
  int* cnt    = (int*)(ws + p); p += n;
  int* ocount = (int*)(ws + p); p += 1;
  p = (p + 3) & ~(size_t)3;  // 16B align
  int* ell    = (int*)(ws + p); p += (size_t)n * ELLK;
  int2* ovf   = (int2*)(ws + p); p += (size_t)OCAP * 2;
  unsigned* A = (unsigned*)(ws + p); p += (size_t)n * 64;  // n*128 bf16
  unsigned* H = (unsigned*)(ws + p); p += (size_t)n * 64;
  unsigned* G = (unsigned*)(ws + p); p += (size_t)n * 64;
  unsigned short* Wt1 = (unsigned short*)(ws + p); p += 8192;  // 128x128 bf16
  unsigned short* Wt2 = (unsigned short*)(ws + p); p += 8192;

  int nbz = (n + 255) / 256;
  int gblk = (n + 63) / 64;
  int epb = (E + gblk - 1) / gblk;  // edges per block for the fused fill

  // 1) zero cnt/ocount + weight transpose
  k_setup<<<nbz + 128, 256, 0, stream>>>(W1, Wmu, Wlv, Wt1, Wt2, cnt, ocount, n, nbz);
  // 2) fused per-block: ELL fill slice + A = bf16(x @ W1)
  k_gemm1_fill<<<gblk, 256, 0, stream>>>(x, Wt1, (unsigned short*)A, ei,
                                         cnt, ell, ovf, ocount, n, E, epb);
  int sblk = (n + 3) / 4;  // one wave per node
  // 3) layer 1: H = bf16(relu(agg(A) + b1))
  k_spmm<true><<<sblk, 256, 0, stream>>>(cnt, ell, ovf, ocount, A, H,
                                         (const float2*)b1, n);
  // 4) layer 2: G = bf16(agg(H))
  k_spmm<false><<<sblk, 256, 0, stream>>>(cnt, ell, ovf, ocount, H, G, nullptr, n);
  // 5) out = [G@Wmu+bmu | G@Wlv+blv]
  k_gemm2_mfma<<<gblk, 256, 0, stream>>>((const unsigned short*)G, Wt2, bmu, blv, out, n);
}